// Round 1
// baseline (289.005 us; speedup 1.0000x reference)
//
#include <hip/hip_runtime.h>
#include <hip/hip_bf16.h>
#include <stdint.h>

#define D_MODEL 1024
#define NHEAD   16
#define HDIM    64
#define BATCH   4
#define SEQ     2048
#define NTOK    (BATCH*SEQ)   // 8192

typedef __bf16          b16x8 __attribute__((ext_vector_type(8)));
typedef unsigned short  u16x8 __attribute__((ext_vector_type(8)));
typedef unsigned short  u16x4 __attribute__((ext_vector_type(4)));
typedef float           f32x4 __attribute__((ext_vector_type(4)));

__device__ __forceinline__ unsigned short f2b(float f) {
  union { float f; uint32_t u; } c; c.f = f;
  return (unsigned short)((c.u + 0x7FFFu + ((c.u >> 16) & 1u)) >> 16);
}

// ---------------- fused QKV projection GEMM ----------------
// C = X(8192x1024) @ W^T(1024x1024), fp32 in, bf16 out (head-interleaved).
// which==0 (Q): scaled by 0.125, layout (b,h,s,dh)
// which==1 (K): layout (b,h,s,dh)
// which==2 (V): layout (b,h,dh,s)  <- transposed for PV B-operand
__global__ __launch_bounds__(256, 2)
void proj_gemm_kernel(const float* __restrict__ q, const float* __restrict__ k,
                      const float* __restrict__ v, const float* __restrict__ Wq,
                      const float* __restrict__ Wk, const float* __restrict__ Wv,
                      unsigned short* __restrict__ qp, unsigned short* __restrict__ kp,
                      unsigned short* __restrict__ vt) {
  __shared__ unsigned short As[2][128 * 40];   // +8 pad: conflict-free frag reads
  __shared__ unsigned short Bs[2][128 * 40];

  int bid = blockIdx.x;
  int swz = (bid & 7) * 192 + (bid >> 3);      // bijective XCD swizzle, 1536 % 8 == 0
  int which = swz >> 9;                        // 0..2
  int rr = swz & 511;
  int tm = rr >> 3, tn = rr & 7;

  const float* X = (which == 0) ? q : ((which == 1) ? k : v);
  const float* W = (which == 0) ? Wq : ((which == 1) ? Wk : Wv);

  int tid  = threadIdx.x;
  int lane = tid & 63;
  int w    = tid >> 6;
  int wr   = (w >> 1) * 64;   // wave quadrant in 128x128 tile
  int wc   = (w & 1) * 64;

  f32x4 acc[4][4];
#pragma unroll
  for (int m = 0; m < 4; m++)
#pragma unroll
    for (int n = 0; n < 4; n++) acc[m][n] = (f32x4){0.f, 0.f, 0.f, 0.f};

  int srow = tid >> 3;   // 0..31
  int sseg = tid & 7;    // 0..7  (8 fp32-quads cover K=32)
  const float* Ag = X + (size_t)(tm * 128 + srow) * D_MODEL + sseg * 4;
  const float* Bg = W + (size_t)(tn * 128 + srow) * D_MODEL + sseg * 4;

  f32x4 ra[4], rb[4];
#pragma unroll
  for (int p = 0; p < 4; p++) {
    ra[p] = *(const f32x4*)(Ag + (size_t)p * 32 * D_MODEL);
    rb[p] = *(const f32x4*)(Bg + (size_t)p * 32 * D_MODEL);
  }
#pragma unroll
  for (int p = 0; p < 4; p++) {            // stage tile 0
    u16x4 ta, tb;
#pragma unroll
    for (int i = 0; i < 4; i++) { ta[i] = f2b(ra[p][i]); tb[i] = f2b(rb[p][i]); }
    *(u16x4*)&As[0][(p * 32 + srow) * 40 + sseg * 4] = ta;
    *(u16x4*)&Bs[0][(p * 32 + srow) * 40 + sseg * 4] = tb;
  }

  for (int kt = 0; kt < 32; kt++) {
    if (kt < 31) {                         // prefetch next K-slab into regs
#pragma unroll
      for (int p = 0; p < 4; p++) {
        ra[p] = *(const f32x4*)(Ag + (size_t)p * 32 * D_MODEL + (kt + 1) * 32);
        rb[p] = *(const f32x4*)(Bg + (size_t)p * 32 * D_MODEL + (kt + 1) * 32);
      }
    }
    __syncthreads();                       // tile kt visible to all waves
    const unsigned short* Ab = As[kt & 1];
    const unsigned short* Bb = Bs[kt & 1];
    int koff = (lane >> 4) * 8;
    u16x8 af[4], bf[4];
#pragma unroll
    for (int m = 0; m < 4; m++)
      af[m] = *(const u16x8*)&Ab[(wr + m * 16 + (lane & 15)) * 40 + koff];
#pragma unroll
    for (int n = 0; n < 4; n++)
      bf[n] = *(const u16x8*)&Bb[(wc + n * 16 + (lane & 15)) * 40 + koff];
#pragma unroll
    for (int m = 0; m < 4; m++)
#pragma unroll
      for (int n = 0; n < 4; n++)
        acc[m][n] = __builtin_amdgcn_mfma_f32_16x16x32_bf16(
            __builtin_bit_cast(b16x8, af[m]), __builtin_bit_cast(b16x8, bf[n]),
            acc[m][n], 0, 0, 0);
    if (kt < 31) {                         // stage tile kt+1 into other buffer
      int nb = (kt + 1) & 1;
#pragma unroll
      for (int p = 0; p < 4; p++) {
        u16x4 ta, tb;
#pragma unroll
        for (int i = 0; i < 4; i++) { ta[i] = f2b(ra[p][i]); tb[i] = f2b(rb[p][i]); }
        *(u16x4*)&As[nb][(p * 32 + srow) * 40 + sseg * 4] = ta;
        *(u16x4*)&Bs[nb][(p * 32 + srow) * 40 + sseg * 4] = tb;
      }
    }
  }

  // epilogue: C/D frag layout: row = (lane>>4)*4+j, col = lane&15
  int cbase = tn * 128 + wc;
  int rbase = tm * 128 + wr;
  if (which < 2) {
    unsigned short* OutP = (which == 0) ? qp : kp;
    float scale = (which == 0) ? 0.125f : 1.0f;   // fold 1/sqrt(Dh) into Q
#pragma unroll
    for (int m = 0; m < 4; m++)
#pragma unroll
      for (int n = 0; n < 4; n++) {
        int e = cbase + n * 16 + (lane & 15);
        int h = e >> 6, dh = e & 63;
#pragma unroll
        for (int j = 0; j < 4; j++) {
          int i = rbase + m * 16 + (lane >> 4) * 4 + j;
          int b = i >> 11, s = i & 2047;
          OutP[(((size_t)(b * NHEAD + h)) * SEQ + s) * HDIM + dh] =
              f2b(acc[m][n][j] * scale);
        }
      }
  } else {  // V: write transposed (b,h,dh,s); 4 consecutive s per lane -> 8B store
#pragma unroll
    for (int m = 0; m < 4; m++)
#pragma unroll
      for (int n = 0; n < 4; n++) {
        int e = cbase + n * 16 + (lane & 15);
        int h = e >> 6, dh = e & 63;
        int i0 = rbase + m * 16 + (lane >> 4) * 4;
        int b = i0 >> 11, s0 = i0 & 2047;
        u16x4 pk;
#pragma unroll
        for (int j = 0; j < 4; j++) pk[j] = f2b(acc[m][n][j]);
        *(u16x4*)&vt[(((size_t)(b * NHEAD + h)) * HDIM + dh) * SEQ + s0] = pk;
      }
  }
}

// ---------------- flash attention ----------------
// grid: 64 (b,h) x 32 q-blocks of 64 rows; 4 waves x 16 q-rows each.
#define KVB 64
__global__ __launch_bounds__(256, 2)
void attn_kernel(const unsigned short* __restrict__ qp,
                 const unsigned short* __restrict__ kp,
                 const unsigned short* __restrict__ vt,
                 float* __restrict__ out) {
  __shared__ unsigned short Kl[64 * 64];   // [key][dh], XOR-swizzled rows
  __shared__ unsigned short Vl[64 * 64];   // [dh][key], XOR-swizzled rows
  __shared__ unsigned short Pl[4 * 16 * 72];

  int bid = blockIdx.x;
  int swz = (bid & 7) * 256 + (bid >> 3);  // bijective XCD swizzle, 2048 % 8 == 0
  int bh = swz >> 5;   // 0..63
  int qb = swz & 31;

  int tid  = threadIdx.x;
  int lane = tid & 63;
  int w    = tid >> 6;

  const unsigned short* Kg = kp + (size_t)bh * SEQ * HDIM;
  const unsigned short* Vg = vt + (size_t)bh * HDIM * SEQ;

  // Q fragments held in registers for the whole kernel (already scaled by 1/8)
  int qrow = qb * 64 + w * 16 + (lane & 15);
  u16x8 aq0 = *(const u16x8*)&qp[((size_t)bh * SEQ + qrow) * HDIM + (lane >> 4) * 8];
  u16x8 aq1 = *(const u16x8*)&qp[((size_t)bh * SEQ + qrow) * HDIM + (lane >> 4) * 8 + 32];

  f32x4 o[4];
#pragma unroll
  for (int d = 0; d < 4; d++) o[d] = (f32x4){0.f, 0.f, 0.f, 0.f};
  float mrun[4], lsum[4];
#pragma unroll
  for (int j = 0; j < 4; j++) { mrun[j] = -1e30f; lsum[j] = 0.f; }

  unsigned short* pw = &Pl[w * 16 * 72];
  int arow = tid >> 3;   // 0..31
  int aseg = tid & 7;

  for (int t = 0; t < SEQ / KVB; t++) {
    int kv0 = t * KVB;
    // ---- stage K tile [64 keys][64 dh] and V^T tile [64 dh][64 keys] ----
#pragma unroll
    for (int i = 0; i < 2; i++) {
      int rowk = arow + i * 32;
      u16x8 kv = *(const u16x8*)&Kg[(size_t)(kv0 + rowk) * HDIM + aseg * 8];
      *(u16x8*)((char*)Kl + rowk * 128 + ((aseg * 16) ^ ((rowk & 7) << 4))) = kv;
      u16x8 vv = *(const u16x8*)&Vg[(size_t)rowk * SEQ + kv0 + aseg * 8];
      *(u16x8*)((char*)Vl + rowk * 128 + ((aseg * 16) ^ ((rowk & 7) << 4))) = vv;
    }
    __syncthreads();

    // ---- S = Q K^T  (4 key-subtiles of 16) ----
    f32x4 sf[4];
#pragma unroll
    for (int st = 0; st < 4; st++) {
      sf[st] = (f32x4){0.f, 0.f, 0.f, 0.f};
      int keyl = st * 16 + (lane & 15);
      u16x8 kf0 = *(const u16x8*)((char*)Kl + keyl * 128 +
                   ((((lane >> 4) * 16)     ) ^ ((keyl & 7) << 4)));
      u16x8 kf1 = *(const u16x8*)((char*)Kl + keyl * 128 +
                   ((((lane >> 4) * 16) + 64) ^ ((keyl & 7) << 4)));
      sf[st] = __builtin_amdgcn_mfma_f32_16x16x32_bf16(
          __builtin_bit_cast(b16x8, aq0), __builtin_bit_cast(b16x8, kf0), sf[st], 0, 0, 0);
      sf[st] = __builtin_amdgcn_mfma_f32_16x16x32_bf16(
          __builtin_bit_cast(b16x8, aq1), __builtin_bit_cast(b16x8, kf1), sf[st], 0, 0, 0);
    }

    // ---- online softmax; row r=(lane>>4)*4+j lives in a 16-lane group ----
#pragma unroll
    for (int j = 0; j < 4; j++) {
      float mx = fmaxf(fmaxf(sf[0][j], sf[1][j]), fmaxf(sf[2][j], sf[3][j]));
      mx = fmaxf(mx, __shfl_xor(mx, 1));
      mx = fmaxf(mx, __shfl_xor(mx, 2));
      mx = fmaxf(mx, __shfl_xor(mx, 4));
      mx = fmaxf(mx, __shfl_xor(mx, 8));
      float mnew = fmaxf(mrun[j], mx);
      float corr = __expf(mrun[j] - mnew);
      mrun[j] = mnew;
      float ps = 0.f;
#pragma unroll
      for (int st = 0; st < 4; st++) {
        float p = __expf(sf[st][j] - mnew);
        pw[((lane >> 4) * 4 + j) * 72 + st * 16 + (lane & 15)] = f2b(p);
        ps += p;
      }
      ps += __shfl_xor(ps, 1); ps += __shfl_xor(ps, 2);
      ps += __shfl_xor(ps, 4); ps += __shfl_xor(ps, 8);
      lsum[j] = lsum[j] * corr + ps;
      o[0][j] *= corr; o[1][j] *= corr; o[2][j] *= corr; o[3][j] *= corr;
    }

    // ---- O += P V  (P via per-wave LDS round-trip; in-order per-wave DS) ----
    u16x8 pa0 = *(const u16x8*)&pw[(lane & 15) * 72 + (lane >> 4) * 8];
    u16x8 pa1 = *(const u16x8*)&pw[(lane & 15) * 72 + (lane >> 4) * 8 + 32];
#pragma unroll
    for (int d = 0; d < 4; d++) {
      int dh = d * 16 + (lane & 15);
      u16x8 vf0 = *(const u16x8*)((char*)Vl + dh * 128 +
                   ((((lane >> 4) * 16)     ) ^ ((dh & 7) << 4)));
      u16x8 vf1 = *(const u16x8*)((char*)Vl + dh * 128 +
                   ((((lane >> 4) * 16) + 64) ^ ((dh & 7) << 4)));
      o[d] = __builtin_amdgcn_mfma_f32_16x16x32_bf16(
          __builtin_bit_cast(b16x8, pa0), __builtin_bit_cast(b16x8, vf0), o[d], 0, 0, 0);
      o[d] = __builtin_amdgcn_mfma_f32_16x16x32_bf16(
          __builtin_bit_cast(b16x8, pa1), __builtin_bit_cast(b16x8, vf1), o[d], 0, 0, 0);
    }
    __syncthreads();   // all waves done with Kl/Vl before next stage
  }

  // epilogue: (B,H,S,Dh) contiguous == reference's raw reshape
#pragma unroll
  for (int d = 0; d < 4; d++) {
    int dh = d * 16 + (lane & 15);
#pragma unroll
    for (int j = 0; j < 4; j++) {
      int row = qb * 64 + w * 16 + (lane >> 4) * 4 + j;
      out[((size_t)bh * SEQ + row) * HDIM + dh] = o[d][j] / lsum[j];
    }
  }
}

extern "C" void kernel_launch(void* const* d_in, const int* in_sizes, int n_in,
                              void* d_out, int out_size, void* d_ws, size_t ws_size,
                              hipStream_t stream) {
  const float* q  = (const float*)d_in[0];
  const float* k  = (const float*)d_in[1];
  const float* v  = (const float*)d_in[2];
  const float* Wq = (const float*)d_in[3];
  const float* Wk = (const float*)d_in[4];
  const float* Wv = (const float*)d_in[5];

  unsigned short* qp = (unsigned short*)d_ws;                 // (B,H,S,Dh) bf16
  unsigned short* kp = qp + (size_t)NTOK * D_MODEL;           // (B,H,S,Dh) bf16
  unsigned short* vt = kp + (size_t)NTOK * D_MODEL;           // (B,H,Dh,S) bf16
  float* out = (float*)d_out;

  hipLaunchKernelGGL(proj_gemm_kernel, dim3(1536), dim3(256), 0, stream,
                     q, k, v, Wq, Wk, Wv, qp, kp, vt);
  hipLaunchKernelGGL(attn_kernel, dim3(2048), dim3(256), 0, stream,
                     qp, kp, vt, out);
}

// Round 2
// 232.239 us; speedup vs baseline: 1.2444x; 1.2444x over previous
//
#include <hip/hip_runtime.h>
#include <hip/hip_bf16.h>
#include <stdint.h>

#define D_MODEL 1024
#define NHEAD   16
#define HDIM    64
#define BATCH   4
#define SEQ     2048
#define NTOK    (BATCH*SEQ)   // 8192

typedef __bf16          b16x8 __attribute__((ext_vector_type(8)));
typedef unsigned short  u16x8 __attribute__((ext_vector_type(8)));
typedef unsigned short  u16x4 __attribute__((ext_vector_type(4)));
typedef float           f32x4 __attribute__((ext_vector_type(4)));
typedef uint32_t        u32x4 __attribute__((ext_vector_type(4)));

__device__ __forceinline__ unsigned short f2b(float f) {
  union { float f; uint32_t u; } c; c.f = f;
  return (unsigned short)((c.u + 0x7FFFu + ((c.u >> 16) & 1u)) >> 16);
}

// packed 2xf32 -> 2xbf16 in one instr (no builtin on gfx950; guide T12)
__device__ __forceinline__ uint32_t cvtpk(float lo, float hi) {
  uint32_t r;
  asm("v_cvt_pk_bf16_f32 %0, %1, %2" : "=v"(r) : "v"(lo), "v"(hi));
  return r;
}

// ---------------- fused QKV projection GEMM ----------------
// C = X(8192x1024) @ W^T(1024x1024), fp32 in, bf16 out (head-interleaved).
// which==0 (Q): scaled by 0.125*log2(e)  (exp2-domain softmax downstream)
// which==1 (K): layout (b,h,s,dh)
// which==2 (V): layout (b,h,dh,s)  <- transposed for PV A-operand
__global__ __launch_bounds__(256, 2)
void proj_gemm_kernel(const float* __restrict__ q, const float* __restrict__ k,
                      const float* __restrict__ v, const float* __restrict__ Wq,
                      const float* __restrict__ Wk, const float* __restrict__ Wv,
                      unsigned short* __restrict__ qp, unsigned short* __restrict__ kp,
                      unsigned short* __restrict__ vt) {
  __shared__ unsigned short As[2][128 * 40];   // +8 pad: conflict-free frag reads
  __shared__ unsigned short Bs[2][128 * 40];

  int bid = blockIdx.x;
  int swz = (bid & 7) * 192 + (bid >> 3);      // bijective XCD swizzle, 1536 % 8 == 0
  int which = swz >> 9;                        // 0..2
  int rr = swz & 511;
  int tm = rr >> 3, tn = rr & 7;

  const float* X = (which == 0) ? q : ((which == 1) ? k : v);
  const float* W = (which == 0) ? Wq : ((which == 1) ? Wk : Wv);

  int tid  = threadIdx.x;
  int lane = tid & 63;
  int w    = tid >> 6;
  int wr   = (w >> 1) * 64;   // wave quadrant in 128x128 tile
  int wc   = (w & 1) * 64;

  f32x4 acc[4][4];
#pragma unroll
  for (int m = 0; m < 4; m++)
#pragma unroll
    for (int n = 0; n < 4; n++) acc[m][n] = (f32x4){0.f, 0.f, 0.f, 0.f};

  int srow = tid >> 3;   // 0..31
  int sseg = tid & 7;    // 0..7  (8 fp32-quads cover K=32)
  const float* Ag = X + (size_t)(tm * 128 + srow) * D_MODEL + sseg * 4;
  const float* Bg = W + (size_t)(tn * 128 + srow) * D_MODEL + sseg * 4;

  f32x4 ra[4], rb[4];
#pragma unroll
  for (int p = 0; p < 4; p++) {
    ra[p] = *(const f32x4*)(Ag + (size_t)p * 32 * D_MODEL);
    rb[p] = *(const f32x4*)(Bg + (size_t)p * 32 * D_MODEL);
  }
#pragma unroll
  for (int p = 0; p < 4; p++) {            // stage tile 0
    u16x4 ta, tb;
#pragma unroll
    for (int i = 0; i < 4; i++) { ta[i] = f2b(ra[p][i]); tb[i] = f2b(rb[p][i]); }
    *(u16x4*)&As[0][(p * 32 + srow) * 40 + sseg * 4] = ta;
    *(u16x4*)&Bs[0][(p * 32 + srow) * 40 + sseg * 4] = tb;
  }

  for (int kt = 0; kt < 32; kt++) {
    if (kt < 31) {                         // prefetch next K-slab into regs
#pragma unroll
      for (int p = 0; p < 4; p++) {
        ra[p] = *(const f32x4*)(Ag + (size_t)p * 32 * D_MODEL + (kt + 1) * 32);
        rb[p] = *(const f32x4*)(Bg + (size_t)p * 32 * D_MODEL + (kt + 1) * 32);
      }
    }
    __syncthreads();                       // tile kt visible to all waves
    const unsigned short* Ab = As[kt & 1];
    const unsigned short* Bb = Bs[kt & 1];
    int koff = (lane >> 4) * 8;
    u16x8 af[4], bf[4];
#pragma unroll
    for (int m = 0; m < 4; m++)
      af[m] = *(const u16x8*)&Ab[(wr + m * 16 + (lane & 15)) * 40 + koff];
#pragma unroll
    for (int n = 0; n < 4; n++)
      bf[n] = *(const u16x8*)&Bb[(wc + n * 16 + (lane & 15)) * 40 + koff];
#pragma unroll
    for (int m = 0; m < 4; m++)
#pragma unroll
      for (int n = 0; n < 4; n++)
        acc[m][n] = __builtin_amdgcn_mfma_f32_16x16x32_bf16(
            __builtin_bit_cast(b16x8, af[m]), __builtin_bit_cast(b16x8, bf[n]),
            acc[m][n], 0, 0, 0);
    if (kt < 31) {                         // stage tile kt+1 into other buffer
      int nb = (kt + 1) & 1;
#pragma unroll
      for (int p = 0; p < 4; p++) {
        u16x4 ta, tb;
#pragma unroll
        for (int i = 0; i < 4; i++) { ta[i] = f2b(ra[p][i]); tb[i] = f2b(rb[p][i]); }
        *(u16x4*)&As[nb][(p * 32 + srow) * 40 + sseg * 4] = ta;
        *(u16x4*)&Bs[nb][(p * 32 + srow) * 40 + sseg * 4] = tb;
      }
    }
  }

  // epilogue: C/D frag layout: row = (lane>>4)*4+j, col = lane&15
  int cbase = tn * 128 + wc;
  int rbase = tm * 128 + wr;
  if (which < 2) {
    unsigned short* OutP = (which == 0) ? qp : kp;
    // Q: fold 1/sqrt(Dh) AND log2(e) so attention uses native exp2
    float scale = (which == 0) ? 0.18033688f : 1.0f;
#pragma unroll
    for (int m = 0; m < 4; m++)
#pragma unroll
      for (int n = 0; n < 4; n++) {
        int e = cbase + n * 16 + (lane & 15);
        int h = e >> 6, dh = e & 63;
#pragma unroll
        for (int j = 0; j < 4; j++) {
          int i = rbase + m * 16 + (lane >> 4) * 4 + j;
          int b = i >> 11, s = i & 2047;
          OutP[(((size_t)(b * NHEAD + h)) * SEQ + s) * HDIM + dh] =
              f2b(acc[m][n][j] * scale);
        }
      }
  } else {  // V: write transposed (b,h,dh,s); 4 consecutive s per lane -> 8B store
#pragma unroll
    for (int m = 0; m < 4; m++)
#pragma unroll
      for (int n = 0; n < 4; n++) {
        int e = cbase + n * 16 + (lane & 15);
        int h = e >> 6, dh = e & 63;
        int i0 = rbase + m * 16 + (lane >> 4) * 4;
        int b = i0 >> 11, s0 = i0 & 2047;
        u16x4 pk;
#pragma unroll
        for (int j = 0; j < 4; j++) pk[j] = f2b(acc[m][n][j]);
        *(u16x4*)&vt[(((size_t)(b * NHEAD + h)) * HDIM + dh) * SEQ + s0] = pk;
      }
  }
}

// ---------------- flash attention v2: swapped QK^T, in-register softmax ----------------
// grid: 64 (b,h) x 32 q-blocks of 64 rows; 4 waves x 16 q-rows each.
// Each lane owns ONE q-row (col c = lane&15); S^T C/D rows are keys (4g+j).
// PV k-slot mapping chosen so P's B-fragment is fully lane-local (zero shuffles).
#define KVB 64
__global__ __launch_bounds__(256, 4)
void attn_kernel(const unsigned short* __restrict__ qp,
                 const unsigned short* __restrict__ kp,
                 const unsigned short* __restrict__ vt,
                 float* __restrict__ out) {
  __shared__ unsigned short Kl[2][64 * 64];   // [key][dh], XOR-swizzled rows
  __shared__ unsigned short Vl[2][64 * 64];   // [dh][key], XOR-swizzled rows

  int bid = blockIdx.x;
  int swz = (bid & 7) * 256 + (bid >> 3);  // bijective XCD swizzle, 2048 % 8 == 0
  int bh = swz >> 5;   // 0..63
  int qb = swz & 31;

  int tid  = threadIdx.x;
  int lane = tid & 63;
  int w    = tid >> 6;
  int g    = lane >> 4;
  int c    = lane & 15;

  const unsigned short* Kg = kp + (size_t)bh * SEQ * HDIM;
  const unsigned short* Vg = vt + (size_t)bh * HDIM * SEQ;

  // Q fragments in registers (pre-scaled by 0.125*log2e in projection)
  int qrow = qb * 64 + w * 16 + c;
  u16x8 aq0 = *(const u16x8*)&qp[((size_t)bh * SEQ + qrow) * HDIM + g * 8];
  u16x8 aq1 = *(const u16x8*)&qp[((size_t)bh * SEQ + qrow) * HDIM + g * 8 + 32];

  f32x4 o[4];
#pragma unroll
  for (int d = 0; d < 4; d++) o[d] = (f32x4){0.f, 0.f, 0.f, 0.f};
  float mrun = -1e30f, lsum = 0.f;

  int arow = tid >> 3;   // 0..31  (staging row)
  int aseg = tid & 7;    // 0..7

  // preload tile 0: global -> regs -> LDS buf0
  u16x8 kreg[2], vreg[2];
#pragma unroll
  for (int i = 0; i < 2; i++) {
    int rowk = arow + i * 32;
    kreg[i] = *(const u16x8*)&Kg[(size_t)rowk * HDIM + aseg * 8];
    vreg[i] = *(const u16x8*)&Vg[(size_t)rowk * SEQ + aseg * 8];
  }
#pragma unroll
  for (int i = 0; i < 2; i++) {
    int rowk = arow + i * 32;
    *(u16x8*)((char*)Kl[0] + rowk * 128 + ((aseg * 16) ^ ((rowk & 7) << 4))) = kreg[i];
    *(u16x8*)((char*)Vl[0] + rowk * 128 + ((aseg * 16) ^ ((rowk & 7) << 4))) = vreg[i];
  }

  for (int t = 0; t < SEQ / KVB; t++) {
    if (t < SEQ / KVB - 1) {       // issue next-tile global loads (consumed post-compute)
      int kv1 = (t + 1) * KVB;
#pragma unroll
      for (int i = 0; i < 2; i++) {
        int rowk = arow + i * 32;
        kreg[i] = *(const u16x8*)&Kg[(size_t)(kv1 + rowk) * HDIM + aseg * 8];
        vreg[i] = *(const u16x8*)&Vg[(size_t)rowk * SEQ + kv1 + aseg * 8];
      }
    }
    __syncthreads();               // buf[t&1] staged; prior reads of buf[(t+1)&1] done
    const unsigned short* Kb = Kl[t & 1];
    const unsigned short* Vb = Vl[t & 1];

    // ---- S^T = K Q^T : lane holds S[key=st*16+4g+j][qrow c] ----
    f32x4 sf[4];
#pragma unroll
    for (int st = 0; st < 4; st++) {
      int keyl = st * 16 + c;
      u16x8 kf0 = *(const u16x8*)((char*)Kb + keyl * 128 +
                   (((g * 16)     ) ^ ((keyl & 7) << 4)));
      u16x8 kf1 = *(const u16x8*)((char*)Kb + keyl * 128 +
                   (((g * 16) + 64) ^ ((keyl & 7) << 4)));
      sf[st] = __builtin_amdgcn_mfma_f32_16x16x32_bf16(
          __builtin_bit_cast(b16x8, kf0), __builtin_bit_cast(b16x8, aq0),
          (f32x4){0.f, 0.f, 0.f, 0.f}, 0, 0, 0);
      sf[st] = __builtin_amdgcn_mfma_f32_16x16x32_bf16(
          __builtin_bit_cast(b16x8, kf1), __builtin_bit_cast(b16x8, aq1),
          sf[st], 0, 0, 0);
    }

    // ---- online softmax, exp2 domain; row-reduce = in-reg + 2 shuffles ----
    float mx = fmaxf(fmaxf(fmaxf(sf[0][0], sf[0][1]), fmaxf(sf[0][2], sf[0][3])),
                     fmaxf(fmaxf(sf[1][0], sf[1][1]), fmaxf(sf[1][2], sf[1][3])));
    mx = fmaxf(mx, fmaxf(fmaxf(fmaxf(sf[2][0], sf[2][1]), fmaxf(sf[2][2], sf[2][3])),
                         fmaxf(fmaxf(sf[3][0], sf[3][1]), fmaxf(sf[3][2], sf[3][3]))));
    mx = fmaxf(mx, __shfl_xor(mx, 16));
    mx = fmaxf(mx, __shfl_xor(mx, 32));
    float mnew = fmaxf(mrun, mx);
    float corr = exp2f(mrun - mnew);
    mrun = mnew;

    float p[4][4];
    float ps = 0.f;
#pragma unroll
    for (int st = 0; st < 4; st++)
#pragma unroll
      for (int j = 0; j < 4; j++) {
        p[st][j] = exp2f(sf[st][j] - mnew);
        ps += p[st][j];
      }
    ps += __shfl_xor(ps, 16);
    ps += __shfl_xor(ps, 32);
    lsum = lsum * corr + ps;
#pragma unroll
    for (int d = 0; d < 4; d++)
#pragma unroll
      for (int j = 0; j < 4; j++) o[d][j] *= corr;

    // ---- pack P to bf16 (lane-local, 8 cvt_pk) ----
    uint32_t pk[8];
#pragma unroll
    for (int st = 0; st < 4; st++) {
      pk[2 * st]     = cvtpk(p[st][0], p[st][1]);
      pk[2 * st + 1] = cvtpk(p[st][2], p[st][3]);
    }

    // ---- O^T += V^T P^T : k-slot (g,e) = key w2*32 + (e>>2)*16 + 4g + (e&3) ----
#pragma unroll
    for (int w2 = 0; w2 < 2; w2++) {
      union { uint32_t u[4]; u16x8 v; } bfu;
      bfu.u[0] = pk[4 * w2];     bfu.u[1] = pk[4 * w2 + 1];
      bfu.u[2] = pk[4 * w2 + 2]; bfu.u[3] = pk[4 * w2 + 3];
#pragma unroll
      for (int d = 0; d < 4; d++) {
        int row = d * 16 + c;
        const char* Vr = (const char*)Vb + row * 128;
        int b0 = w2 * 64 + g * 8;
        union { u16x4 h[2]; u16x8 v; } afu;
        afu.h[0] = *(const u16x4*)(Vr + ((b0     ) ^ ((row & 7) << 4)));
        afu.h[1] = *(const u16x4*)(Vr + ((b0 + 32) ^ ((row & 7) << 4)));
        o[d] = __builtin_amdgcn_mfma_f32_16x16x32_bf16(
            __builtin_bit_cast(b16x8, afu.v), __builtin_bit_cast(b16x8, bfu.v),
            o[d], 0, 0, 0);
      }
    }

    if (t < SEQ / KVB - 1) {       // stage t+1 into other buffer
      int nb = (t + 1) & 1;
#pragma unroll
      for (int i = 0; i < 2; i++) {
        int rowk = arow + i * 32;
        *(u16x8*)((char*)Kl[nb] + rowk * 128 + ((aseg * 16) ^ ((rowk & 7) << 4))) = kreg[i];
        *(u16x8*)((char*)Vl[nb] + rowk * 128 + ((aseg * 16) ^ ((rowk & 7) << 4))) = vreg[i];
      }
    }
  }

  // epilogue: o[d][j] = O[qrow][dh=d*16+4g+j]; 16B f32x4 stores
  float inv = 1.f / lsum;
  float* orow = out + ((size_t)bh * SEQ + qrow) * HDIM;
#pragma unroll
  for (int d = 0; d < 4; d++) {
    f32x4 val;
#pragma unroll
    for (int j = 0; j < 4; j++) val[j] = o[d][j] * inv;
    *(f32x4*)(orow + d * 16 + g * 4) = val;
  }
}

extern "C" void kernel_launch(void* const* d_in, const int* in_sizes, int n_in,
                              void* d_out, int out_size, void* d_ws, size_t ws_size,
                              hipStream_t stream) {
  const float* q  = (const float*)d_in[0];
  const float* k  = (const float*)d_in[1];
  const float* v  = (const float*)d_in[2];
  const float* Wq = (const float*)d_in[3];
  const float* Wk = (const float*)d_in[4];
  const float* Wv = (const float*)d_in[5];

  unsigned short* qp = (unsigned short*)d_ws;                 // (B,H,S,Dh) bf16
  unsigned short* kp = qp + (size_t)NTOK * D_MODEL;           // (B,H,S,Dh) bf16
  unsigned short* vt = kp + (size_t)NTOK * D_MODEL;           // (B,H,Dh,S) bf16
  float* out = (float*)d_out;

  hipLaunchKernelGGL(proj_gemm_kernel, dim3(1536), dim3(256), 0, stream,
                     q, k, v, Wq, Wk, Wv, qp, kp, vt);
  hipLaunchKernelGGL(attn_kernel, dim3(2048), dim3(256), 0, stream,
                     qp, kp, vt, out);
}